// Round 7
// baseline (235.600 us; speedup 1.0000x reference)
//
#include <hip/hip_runtime.h>
#include <hip/hip_bf16.h>
#include <math.h>

typedef __bf16 bf16x8 __attribute__((ext_vector_type(8)));
typedef float f32x4 __attribute__((ext_vector_type(4)));

#define GAS __attribute__((address_space(1)))
#define LAS __attribute__((address_space(3)))

static __device__ __forceinline__ void load16(const void* g, void* l) {
    __builtin_amdgcn_global_load_lds((const GAS void*)g, (LAS void*)l, 16, 0, 0);
}

struct __align__(8) bh4 { __hip_bfloat16 x, y, z, w; };

// ---------- prep: LN row-stats (blocks 0..nln-1) + weight cast w/ gamma fold
// ---------- (nln..nln+1023) + b1' = b1 + W1·beta GEMV (last 32 blocks) ----------
// LN itself is folded into gemm0: W1·(xhat*gamma+beta)+b1 = (W1 .* gamma)·xhat
// + (b1 + W1·beta). pre now writes 128 KB of stats instead of 33.5 MB of hn.
__global__ __launch_bounds__(256) void prep_kernel(
        const float* __restrict__ x, const float* __restrict__ gamma,
        const float* __restrict__ beta, const float* __restrict__ w1,
        const float* __restrict__ w2, const float* __restrict__ b1,
        float2* __restrict__ stats, __hip_bfloat16* __restrict__ w1g,
        __hip_bfloat16* __restrict__ w2b, float* __restrict__ b1g, int nln) {
    const int bid = blockIdx.x;
    const int tid = threadIdx.x;
    if (bid >= nln + 1024) {                 // ---- GEMV: 32 blocks, 32 outputs each
        const int e    = (bid - nln - 1024) * 32 + (tid >> 3);
        const int part = tid & 7;
        const float4* wrow = (const float4*)(w1 + (size_t)e * 1024 + part * 128);
        const float4* bet  = (const float4*)(beta + part * 128);
        float s = 0.f;
#pragma unroll 8
        for (int i = 0; i < 32; ++i) {
            float4 wv = wrow[i], bv = bet[i];
            s += wv.x * bv.x + wv.y * bv.y + wv.z * bv.z + wv.w * bv.w;
        }
        s += __shfl_xor(s, 1, 64);
        s += __shfl_xor(s, 2, 64);
        s += __shfl_xor(s, 4, 64);
        if (part == 0) b1g[e] = b1[e] + s;
        return;
    }
    if (bid >= nln) {                        // ---- weight cast (w1 folds gamma)
        const int i = (bid - nln) * 256 + tid;
        float4 a = ((const float4*)w1)[i];
        float4 g = ((const float4*)gamma)[i & 255];   // 256 float4 per row
        float4 b = ((const float4*)w2)[i];
        bh4 r1, r2;
        r1.x = __float2bfloat16(a.x * g.x); r1.y = __float2bfloat16(a.y * g.y);
        r1.z = __float2bfloat16(a.z * g.z); r1.w = __float2bfloat16(a.w * g.w);
        r2.x = __float2bfloat16(b.x); r2.y = __float2bfloat16(b.y);
        r2.z = __float2bfloat16(b.z); r2.w = __float2bfloat16(b.w);
        ((bh4*)w1g)[i] = r1;
        ((bh4*)w2b)[i] = r2;
        return;
    }
    // ---- row stats: 4 rows/block, one wave per row
    const int row  = (bid << 2) + (tid >> 6);
    const int lane = tid & 63;
    const float4* px = (const float4*)(x + (size_t)row * 1024);
    float4 v[4];
    float s = 0.f;
#pragma unroll
    for (int i = 0; i < 4; ++i) {
        v[i] = px[lane + (i << 6)];
        s += v[i].x + v[i].y + v[i].z + v[i].w;
    }
#pragma unroll
    for (int o = 32; o; o >>= 1) s += __shfl_xor(s, o, 64);
    const float mu = s * (1.0f / 1024.0f);
    float vs = 0.f;
#pragma unroll
    for (int i = 0; i < 4; ++i) {
        float a = v[i].x - mu, b = v[i].y - mu, c = v[i].z - mu, d = v[i].w - mu;
        vs += a * a + b * b + c * c + d * d;
    }
#pragma unroll
    for (int o = 32; o; o >>= 1) vs += __shfl_xor(vs, o, 64);
    if (lane == 0) {
        float2 st;
        st.x = mu;
        st.y = rsqrtf(vs * (1.0f / 1024.0f) + 1e-5f);
        stats[row] = st;
    }
}

// fast exact-GELU: erf via Abramowitz-Stegun 7.1.26 (|eps| <= 1.5e-7, branchless).
__device__ __forceinline__ float gelu_exact(float v) {
    const float ax = fabsf(v) * 0.70710678118654752f;
    const float t  = __builtin_amdgcn_rcpf(__builtin_fmaf(0.3275911f, ax, 1.0f));
    float p = __builtin_fmaf(1.061405429f, t, -1.453152027f);
    p = __builtin_fmaf(p, t, 1.421413741f);
    p = __builtin_fmaf(p, t, -0.284496736f);
    p = __builtin_fmaf(p, t, 0.254829592f);
    p *= t;
    const float e  = __expf(-ax * ax);
    const float er = __builtin_fmaf(-p, e, 1.0f);     // erf(|x|) in [0,1)
    return 0.5f * v * (1.0f + copysignf(er, v));
}

// ============== 128x128 GEMM (B^T weights), BK=64 dbuf, mfma 16x16x32 =============
// Round-6 structure unchanged (2 blocks/CU, 64 KiB LDS, 1 bar/tile, front-loaded
// ds_reads + counted lgkm, vmcnt(0)+bar at tile end).
// EPI==0 (gemm0): A is LayerNorm'd x, reg-staged on the fly: per 16-B A-chunk,
//   load 32 B of f32 x (L3-resident; pre just read it), (v-mu)*rs, cvt bf16,
//   ds_write to the SAME swizzled LDS image as the gload_lds path (phys chunk
//   p = logical ^ (row&7); we write logical l=tid&7's data at phys l^key).
//   vmcnt ledger per tile: 8 x-loads, then 4 B-gloads -> VMW(4) after MFMA
//   retires exactly the x-loads; normalize+ds_write+lgkm0; caller VMW(0) lands B.
// EPI==1 (gemm1): identical to round 6.
#define SCB() __builtin_amdgcn_sched_barrier(0)
#define BAR() do { __builtin_amdgcn_s_barrier(); SCB(); } while (0)
#define LGKM(n) do { asm volatile("s_waitcnt lgkmcnt(" #n ")" ::: "memory"); SCB(); } while (0)
#define VMW(n) do { asm volatile("s_waitcnt vmcnt(" #n ")" ::: "memory"); SCB(); } while (0)

__device__ __forceinline__ void rd4(const char* base, int stride, bf16x8 (&v)[4]) {
#pragma unroll
    for (int i = 0; i < 4; ++i) v[i] = *(const bf16x8*)(base + i * stride);
}

#define MFMA16(AF, BF) do { __builtin_amdgcn_s_setprio(1); \
    _Pragma("unroll") for (int i2 = 0; i2 < 4; ++i2) \
    _Pragma("unroll") for (int j2 = 0; j2 < 4; ++j2) \
        acc[i2][j2] = __builtin_amdgcn_mfma_f32_16x16x32_bf16(AF[i2], BF[j2], acc[i2][j2], 0, 0, 0); \
    __builtin_amdgcn_s_setprio(0); } while (0)

// KOFF in f32/bf16 elements (k-index). 8 x-loads for the NEXT tile's A half.
#define XLOAD(KOFF) do { _Pragma("unroll") for (int q = 0; q < 4; ++q) { \
    const float4* p_ = (const float4*)(xs + (KOFF) + q * 32768); \
    xv[q][0] = p_[0]; xv[q][1] = p_[1]; } } while (0)

#define XSTORE(OTH) do { _Pragma("unroll") for (int q = 0; q < 4; ++q) { \
    const float mu_ = st4[q].x, rs_ = st4[q].y; \
    const float4 a_ = xv[q][0], b_ = xv[q][1]; \
    bf16x8 r_; \
    r_[0] = (__bf16)((a_.x - mu_) * rs_); r_[1] = (__bf16)((a_.y - mu_) * rs_); \
    r_[2] = (__bf16)((a_.z - mu_) * rs_); r_[3] = (__bf16)((a_.w - mu_) * rs_); \
    r_[4] = (__bf16)((b_.x - mu_) * rs_); r_[5] = (__bf16)((b_.y - mu_) * rs_); \
    r_[6] = (__bf16)((b_.z - mu_) * rs_); r_[7] = (__bf16)((b_.w - mu_) * rs_); \
    *(bf16x8*)(dAw + (OTH) * 16384 + q * 4096) = r_; } } while (0)

#define TILE128(CUR, OTH, KOFF, S1) do { \
    const char* aB_ = aBase + (CUR) * 16384; \
    const char* bB_ = bBase + (CUR) * 16384; \
    if (EPI == 0 && (S1)) { XLOAD((KOFF) + 64); } \
    rd4(aB_ + px0, 2048, af0); SCB(); \
    rd4(bB_ + px0, 128, bf0); SCB(); \
    rd4(aB_ + px1, 2048, af1); SCB(); \
    rd4(bB_ + px1, 128, bf1); SCB(); \
    if (S1) { \
        char* dBo = dB + (OTH) * 16384; \
        load16(sb + (KOFF) + 64,             dBo); \
        load16(sb + (KOFF) + 64 + 32 * 1024, dBo + 4096); \
        load16(sb + (KOFF) + 64 + 64 * 1024, dBo + 8192); \
        load16(sb + (KOFF) + 64 + 96 * 1024, dBo + 12288); \
        if (EPI == 1) { \
            char* dAo = dA + (OTH) * 16384; \
            load16(sa + (KOFF) + 64,             dAo); \
            load16(sa + (KOFF) + 64 + 32 * 1024, dAo + 4096); \
            load16(sa + (KOFF) + 64 + 64 * 1024, dAo + 8192); \
            load16(sa + (KOFF) + 64 + 96 * 1024, dAo + 12288); \
        } \
    } \
    LGKM(8); \
    MFMA16(af0, bf0); \
    LGKM(0); \
    MFMA16(af1, bf1); \
    if (EPI == 0 && (S1)) { VMW(4); XSTORE(OTH); LGKM(0); } \
} while (0)

template <int EPI>
__global__ __launch_bounds__(256, 2) void gemm128(
        const __hip_bfloat16* __restrict__ A,
        const __hip_bfloat16* __restrict__ B,
        const float* __restrict__ bias,
        const float* __restrict__ resid,
        __hip_bfloat16* __restrict__ outb,
        float* __restrict__ outf,
        const float* __restrict__ xsrc,
        const float2* __restrict__ stats) {
    constexpr int K = 1024, N = 1024;
    __shared__ __align__(16) char sA[32768];   // 2 x 16K A buffers
    __shared__ __align__(16) char sB[32768];   // 2 x 16K B buffers

    const int tid  = threadIdx.x;
    const int lane = tid & 63;
    const int w    = tid >> 6;
    const int wm   = (w >> 1) * 64;   // wave row base in tile
    const int wn   = (w & 1) * 64;    // wave col base in tile
    const int bm   = blockIdx.x * 128;
    const int bn   = blockIdx.y * 128;

    const int f = lane & 15;
    const int h = lane >> 4;

    // staging geometry (identity rows, column chunk permuted per swizzle)
    const int srow = tid >> 3;                         // row within 32-row group
    const int lA_chunk = (tid & 7) ^ (srow & 7);       // sA swizzle key = row&7
    const int lB_chunk = (tid & 7) ^ ((tid >> 5) & 7); // sB key = (row>>2)&7
    const __hip_bfloat16* sa = A + (size_t)(bm + srow) * K + lA_chunk * 8;
    const __hip_bfloat16* sb = B + (size_t)(bn + srow) * K + lB_chunk * 8;
    char* dA = sA + tid * 16;   // linear gload dst: per-wave uniform base + lane*16
    char* dB = sB + tid * 16;

    // LN-A reg-staging geometry (EPI==0): linear logical chunk l = tid&7,
    // ds_write dst at phys chunk l ^ (srow&7) -> identical LDS image.
    const float* xs = xsrc + (size_t)(bm + srow) * 1024 + (tid & 7) * 8;
    char* dAw = sA + srow * 128 + (((tid & 7) ^ (srow & 7)) << 4);
    float2 st4[4];
    float4 xv[4][2];

    // fragment read bases (verified round-0 layout)
    const int pxk = (f & 7) * 16;
    const int px0 = (h * 16) ^ pxk;
    const int px1 = ((4 + h) * 16) ^ pxk;
    const char* aBase = sA + (wm + f) * 128;
    const char* bBase = sB + (wn + 4 * f) * 128;

    f32x4 acc[4][4] = {};
    bf16x8 af0[4], af1[4], bf0[4], bf1[4];

    // prologue: tile0 -> buf0; drain; barrier.
    if (EPI == 0) {
        // ledger: 4 stats + 8 x + 4 B = 16 vm ops; VMW(4) retires stats+x.
#pragma unroll
        for (int q = 0; q < 4; ++q) st4[q] = stats[bm + srow + 32 * q];
        XLOAD(0);
        load16(sb, dB);                     load16(sb + 32 * 1024, dB + 4096);
        load16(sb + 64 * 1024, dB + 8192);  load16(sb + 96 * 1024, dB + 12288);
        VMW(4);
        XSTORE(0);
        LGKM(0);
        VMW(0);
    } else {
        load16(sa, dA);                     load16(sb, dB);
        load16(sa + 32 * 1024, dA + 4096);  load16(sb + 32 * 1024, dB + 4096);
        load16(sa + 64 * 1024, dA + 8192);  load16(sb + 64 * 1024, dB + 8192);
        load16(sa + 96 * 1024, dA + 12288); load16(sb + 96 * 1024, dB + 12288);
        VMW(0);
    }
    BAR();

#pragma unroll 1
    for (int it = 0; it < 7; ++it) {          // t = 0..13
        const int k0 = it << 7;
        TILE128(0, 1, k0, true);
        VMW(0); BAR();
        TILE128(1, 0, k0 + 64, true);
        VMW(0); BAR();
    }
    // t = 14: stage tile-15 -> buf1; drain; barrier
    TILE128(0, 1, 896, true);
    VMW(0); BAR();
    // t = 15: no stages, no end sync
    TILE128(1, 0, 960, false);

    // epilogue: lane owns rows bm+wm+i*16+h*4+r, 4 contiguous cols bn+wn+4f..+3
    const int colb = bn + wn + f * 4;
    const float4 bias4 = *(const float4*)(bias + colb);
#pragma unroll
    for (int i = 0; i < 4; ++i) {
#pragma unroll
        for (int r = 0; r < 4; ++r) {
            const size_t grow = (size_t)(bm + wm + i * 16 + h * 4 + r);
            float v0 = acc[i][0][r] + bias4.x;
            float v1 = acc[i][1][r] + bias4.y;
            float v2 = acc[i][2][r] + bias4.z;
            float v3 = acc[i][3][r] + bias4.w;
            if (EPI == 0) {
                bh4 o;
                o.x = __float2bfloat16(gelu_exact(v0));
                o.y = __float2bfloat16(gelu_exact(v1));
                o.z = __float2bfloat16(gelu_exact(v2));
                o.w = __float2bfloat16(gelu_exact(v3));
                *(bh4*)(outb + grow * N + colb) = o;
            } else {
                const float4 rs = *(const float4*)(resid + grow * N + colb);
                float4 o = {v0 + rs.x, v1 + rs.y, v2 + rs.z, v3 + rs.w};
                *(float4*)(outf + grow * N + colb) = o;
            }
        }
    }
}

extern "C" void kernel_launch(void* const* d_in, const int* in_sizes, int n_in,
                              void* d_out, int out_size, void* d_ws, size_t ws_size,
                              hipStream_t stream) {
    const float* x     = (const float*)d_in[0];
    const float* gamma = (const float*)d_in[1];
    const float* beta  = (const float*)d_in[2];
    const float* w1    = (const float*)d_in[3];
    const float* b1    = (const float*)d_in[4];
    const float* w2    = (const float*)d_in[5];
    const float* b2    = (const float*)d_in[6];
    float* out = (float*)d_out;

    const int M = in_sizes[0] / 1024;   // 16384

    char* ws = (char*)d_ws;
    __hip_bfloat16* h1  = (__hip_bfloat16*)ws;                            // 32 MiB
    __hip_bfloat16* w1g = (__hip_bfloat16*)(ws + (size_t)M * 2048);       // 2 MiB
    __hip_bfloat16* w2b = (__hip_bfloat16*)(ws + (size_t)M * 2048 + 2097152);
    float*          b1g = (float*)(ws + (size_t)M * 2048 + 4194304);      // 4 KiB
    float2*       stats = (float2*)(ws + (size_t)M * 2048 + 4198400);     // 128 KiB

    const int nln = M / 4;   // 4096 stats blocks + 1024 cast + 32 GEMV
    prep_kernel<<<nln + 1024 + 32, 256, 0, stream>>>(
        x, gamma, beta, w1, w2, b1, stats, w1g, w2b, b1g, nln);
    // grid x = bm: linear id % 8 = bm % 8 -> same-bm blocks share an XCD (A-strip
    // L2 reuse); 1024 blocks = 4/CU (2 resident via 64KB LDS).
    gemm128<0><<<dim3(M / 128, 8), 256, 0, stream>>>(
        (const __hip_bfloat16*)x, w1g, b1g, nullptr, h1, nullptr, x, stats);
    gemm128<1><<<dim3(M / 128, 8), 256, 0, stream>>>(
        h1, w2b, b2, x, nullptr, out, x, stats);
}